// Round 4
// baseline (1367.411 us; speedup 1.0000x reference)
//
#include <hip/hip_runtime.h>
#include <math.h>

// ---------------------------------------------------------------------------
// SimpleLESS4FDModel: 2-layer HGT on a homogeneous graph.
// a_rel / m_rel folded into projection weights (fold_weights).
// Per edge:  alpha = <kt[src], q[dst]>_head * p_rel / 4 ;
//   agg[dst] = sum_e exp(alpha) * vt[src] / (sum_e exp(alpha) + 1e-16)
// CSR (built once, reused by both layers) makes aggregation atomic-free.
//
// R1 lesson: no runtime-indexed local arrays (forces scratch).
// R2 lesson: bound all big-loop unrolls; cap VGPRs via __launch_bounds__.
// R3: fp32 vector GEMM is LDS-pipe-bound (3 ds_read_b128 per 32 FMA, 4 SIMDs
// share 1 LDS pipe -> VALUBusy 32%). Switch to split-bf16 MFMA:
//   a*b ~= ah*bh + ah*bl + al*bh  (al*bl ~ 2^-16 rel, dropped)
// A-fragments load STRAIGHT from row-major global (A[m=lane&15][k=quad*8+j]
// is k-contiguous); B comes from a once-per-launch transposed+split copy
// Wt[c][k] so B-frags are also contiguous 16B loads. No LDS, no barriers.
// ---------------------------------------------------------------------------

typedef __attribute__((ext_vector_type(8))) short bf16x8;  // 8 bf16 (4 VGPRs)
typedef __attribute__((ext_vector_type(4))) float f32x4;

__device__ __forceinline__ float gelu_t(float x) {
  const float c = 0.7978845608028654f;  // sqrt(2/pi)
  float t = tanhf(c * (x + 0.044715f * x * x * x));
  return 0.5f * x * (1.0f + t);
}

// split fp32 -> bf16 hi (truncate) + bf16 lo (truncate of remainder)
__device__ __forceinline__ void split1(float a, ushort& h, ushort& l) {
  unsigned u = __float_as_uint(a);
  unsigned uh = u & 0xffff0000u;
  float fl = a - __uint_as_float(uh);
  h = (ushort)(uh >> 16);
  l = (ushort)(__float_as_uint(fl) >> 16);
}

// ---------------- split-bf16 MFMA GEMM ---------------------------------------
// out[r, colBlk+c] = epi(A[r,:] @ W[:,c] + bias[c])
// Block: 256 threads = 4 waves; wave w computes rows (blk*64 + w*16 .. +15)
// x 64 cols (4 MFMA col-tiles). Wt_h/Wt_l are [C][K] bf16 (k-contiguous).
template<int K, bool PRE_GELU, bool EPI_SKIP>
__global__ __launch_bounds__(256, 4)
void mfma_gemm(const float* __restrict__ A, int ldA,
               const ushort* __restrict__ Wt_h, const ushort* __restrict__ Wt_l,
               const float* __restrict__ bias,
               const float* __restrict__ Hprev,
               const float* __restrict__ skipPtr,
               float* __restrict__ outp, int ldOut, int nRows)
{
  const int lane = threadIdx.x & 63;
  const int wave = threadIdx.x >> 6;
  const int m = lane & 15;   // A row within tile; B/C col within tile
  const int q = lane >> 4;   // quad: A/B k-group, C row-group
  const int tileRow0 = blockIdx.x * 64 + wave * 16;
  const int colBlk = blockIdx.y * 64;

  const int rowA = tileRow0 + m;
  const int rowL = (rowA < nRows) ? rowA : (nRows - 1);  // clamp; OOB rows masked at store
  const float* aptr = A + (size_t)rowL * ldA + q * 8;

  f32x4 acc[4];
#pragma unroll
  for (int ct = 0; ct < 4; ++ct) acc[ct] = (f32x4){0.f, 0.f, 0.f, 0.f};

#pragma clang loop unroll(disable)
  for (int kc = 0; kc < K; kc += 32) {
    float4 a0 = *(const float4*)(aptr + kc);
    float4 a1 = *(const float4*)(aptr + kc + 4);
    float av[8] = {a0.x, a0.y, a0.z, a0.w, a1.x, a1.y, a1.z, a1.w};
    if (PRE_GELU) {
#pragma unroll
      for (int j = 0; j < 8; ++j) av[j] = gelu_t(av[j]);
    }
    bf16x8 ah, al;
#pragma unroll
    for (int j = 0; j < 8; ++j) {
      ushort h, l; split1(av[j], h, l);
      ah[j] = (short)h; al[j] = (short)l;
    }
#pragma unroll
    for (int ct = 0; ct < 4; ++ct) {
      size_t boff = (size_t)(colBlk + ct * 16 + m) * K + kc + q * 8;
      bf16x8 bh = *(const bf16x8*)(Wt_h + boff);
      bf16x8 bl = *(const bf16x8*)(Wt_l + boff);
      acc[ct] = __builtin_amdgcn_mfma_f32_16x16x32_bf16(ah, bh, acc[ct], 0, 0, 0);
      acc[ct] = __builtin_amdgcn_mfma_f32_16x16x32_bf16(ah, bl, acc[ct], 0, 0, 0);
      acc[ct] = __builtin_amdgcn_mfma_f32_16x16x32_bf16(al, bh, acc[ct], 0, 0, 0);
    }
  }

  // epilogue: C/D layout col = lane&15 (=m), row = quad*4 + reg  [m89-verified]
  float g = 0.f, gi = 0.f;
  if (EPI_SKIP) { g = 1.0f / (1.0f + __expf(-skipPtr[0])); gi = 1.0f - g; }
#pragma unroll
  for (int ct = 0; ct < 4; ++ct) {
    int c = colBlk + ct * 16 + m;
    float b = bias[c];
#pragma unroll
    for (int i = 0; i < 4; ++i) {
      int r = tileRow0 + q * 4 + i;
      if (r < nRows) {
        float o = acc[ct][i] + b;
        if (EPI_SKIP) {
          float hp = Hprev[(size_t)r * 64 + c];
          o = fmaxf(g * o + gi * hp, 0.f);
        }
        outp[(size_t)r * ldOut + c] = o;
      }
    }
  }
}

// ---------------- weight transpose + bf16 split (once per launch) ------------
// W[k][c] (row-major, ld=C) -> Wt_h/Wt_l[c][k] bf16
__global__ void prep_weights(const float* __restrict__ W, int K, int C,
                             ushort* __restrict__ Wt_h, ushort* __restrict__ Wt_l)
{
  int idx = blockIdx.x * 256 + threadIdx.x;
  if (idx < K * C) {
    int k = idx / C, c = idx % C;
    ushort h, l; split1(W[idx], h, l);
    Wt_h[(size_t)c * K + k] = h;
    Wt_l[(size_t)c * K + k] = l;
  }
}

// ---------------- fold a_rel / m_rel into packed qkv weights ------------------
// Wqkv[l]: [64][192]  cols 0..63 = Wq, 64..127 = Wk@BD(a_rel), 128..191 = Wv@BD(m_rel)
__global__ void fold_weights(const float* __restrict__ Wq, const float* __restrict__ bq,
                             const float* __restrict__ Wk, const float* __restrict__ bk,
                             const float* __restrict__ Wv, const float* __restrict__ bv,
                             const float* __restrict__ a_rel, const float* __restrict__ m_rel,
                             float* __restrict__ Wqkv, float* __restrict__ bqkv)
{
  int l = blockIdx.x;
  const float* wq = Wq + l * 4096; const float* wk = Wk + l * 4096; const float* wv = Wv + l * 4096;
  const float* bql = bq + l * 64;  const float* bkl = bk + l * 64;  const float* bvl = bv + l * 64;
  const float* ar = a_rel + l * 1024; const float* mr = m_rel + l * 1024;
  float* W = Wqkv + l * 64 * 192;  float* B = bqkv + l * 192;
  for (int t = threadIdx.x; t < 64 * 192; t += blockDim.x) {
    int i = t / 192, c = t % 192;
    float val;
    if (c < 64) {
      val = wq[i * 64 + c];
    } else if (c < 128) {
      int cc = c - 64, hh = cc >> 4, f = cc & 15;
      float s = 0.f;
      for (int d = 0; d < 16; ++d) s += wk[i * 64 + hh * 16 + d] * ar[hh * 256 + d * 16 + f];
      val = s;
    } else {
      int cc = c - 128, hh = cc >> 4, f = cc & 15;
      float s = 0.f;
      for (int d = 0; d < 16; ++d) s += wv[i * 64 + hh * 16 + d] * mr[hh * 256 + d * 16 + f];
      val = s;
    }
    W[i * 192 + c] = val;
  }
  for (int c = threadIdx.x; c < 192; c += blockDim.x) {
    float val;
    if (c < 64) {
      val = bql[c];
    } else if (c < 128) {
      int cc = c - 64, hh = cc >> 4, f = cc & 15;
      float s = 0.f;
      for (int d = 0; d < 16; ++d) s += bkl[hh * 16 + d] * ar[hh * 256 + d * 16 + f];
      val = s;
    } else {
      int cc = c - 128, hh = cc >> 4, f = cc & 15;
      float s = 0.f;
      for (int d = 0; d < 16; ++d) s += bvl[hh * 16 + d] * mr[hh * 256 + d * 16 + f];
      val = s;
    }
    B[c] = val;
  }
}

// ---------------- CSR construction -------------------------------------------
__global__ void hist_kernel(const int* __restrict__ dst, int* __restrict__ counts, int E) {
  int e = blockIdx.x * 256 + threadIdx.x;
  if (e < E) atomicAdd(&counts[dst[e]], 1);
}

__global__ __launch_bounds__(256)
void scanA(int* __restrict__ counts, int* __restrict__ blockSums, int n) {
  __shared__ int sd[256];
  int tid = threadIdx.x;
  int base = blockIdx.x * 1024 + tid * 4;
  int v[4];
#pragma unroll
  for (int j = 0; j < 4; ++j) v[j] = (base + j < n) ? counts[base + j] : 0;
  int t = v[0] + v[1] + v[2] + v[3];
  sd[tid] = t; __syncthreads();
  for (int offm = 1; offm < 256; offm <<= 1) {
    int adj = (tid >= offm) ? sd[tid - offm] : 0;
    __syncthreads();
    sd[tid] += adj;
    __syncthreads();
  }
  int run = sd[tid] - t;  // exclusive prefix for this thread
#pragma unroll
  for (int j = 0; j < 4; ++j) {
    if (base + j < n) counts[base + j] = run;
    run += v[j];
  }
  if (tid == 255) blockSums[blockIdx.x] = sd[255];
}

__global__ void scanB(int* __restrict__ blockSums, int G, int* __restrict__ row_ptr, int n) {
  __shared__ int sd[128];
  int tid = threadIdx.x;
  int t = (tid < G) ? blockSums[tid] : 0;
  sd[tid] = t; __syncthreads();
  for (int offm = 1; offm < 128; offm <<= 1) {
    int adj = (tid >= offm) ? sd[tid - offm] : 0;
    __syncthreads();
    sd[tid] += adj;
    __syncthreads();
  }
  if (tid < G) blockSums[tid] = sd[tid] - t;
  if (tid == 127) row_ptr[n] = sd[127];  // total = E
}

__global__ void scanC(const int* __restrict__ counts, const int* __restrict__ blockSums,
                      int* __restrict__ row_ptr, int* __restrict__ cursor, int n) {
  int idx = blockIdx.x * 256 + threadIdx.x;
  if (idx < n) {
    int v = counts[idx] + blockSums[idx >> 10];
    row_ptr[idx] = v;
    cursor[idx] = v;
  }
}

__global__ void scatter_kernel(const int* __restrict__ src, const int* __restrict__ dst,
                               int* __restrict__ cursor, int* __restrict__ csr_src, int E) {
  int e = blockIdx.x * 256 + threadIdx.x;
  if (e < E) {
    int d = dst[e];
    int pos = atomicAdd(&cursor[d], 1);
    csr_src[pos] = src[e];
  }
}

// ---------------- fused attention aggregation: one wave per dst node ----------
// lane = head*16 + f. qkv row layout: [q(64) | kt(64) | vt(64)], ld=192.
__global__ __launch_bounds__(256)
void edge_agg(const float* __restrict__ qkv, const int* __restrict__ row_ptr,
              const int* __restrict__ csr_src, const float* __restrict__ p_rel,
              float* __restrict__ agg, int n)
{
  int wid = blockIdx.x * 4 + (threadIdx.x >> 6);
  if (wid >= n) return;
  int lane = threadIdx.x & 63;
  int head = lane >> 4;
  float pr = p_rel[head] * 0.25f;  // p_rel / sqrt(D), D=16
  float qv = qkv[(size_t)wid * 192 + lane];
  int e0 = row_ptr[wid], e1 = row_ptr[wid + 1];
  float num = 0.f, den = 0.f;
  for (int e = e0; e < e1; ++e) {
    int s = csr_src[e];
    const float* base = qkv + (size_t)s * 192;
    float ktv = base[64 + lane];
    float vtv = base[128 + lane];
    float p = ktv * qv;
    p += __shfl_xor(p, 1);
    p += __shfl_xor(p, 2);
    p += __shfl_xor(p, 4);
    p += __shfl_xor(p, 8);   // per-head dot over 16 lanes
    float w = __expf(p * pr);
    den += w;
    num = fmaf(w, vtv, num);
  }
  agg[(size_t)wid * 64 + lane] = num / (den + 1e-16f);
}

// ---------------- classifier: 64 -> relu(32) -> 2 ----------------------------
__global__ __launch_bounds__(256)
void classifier(const float* __restrict__ h, const float* __restrict__ Wc1,
                const float* __restrict__ bc1, const float* __restrict__ Wc2,
                const float* __restrict__ bc2, float* __restrict__ out, int n)
{
  int row = blockIdx.x * 256 + threadIdx.x;
  if (row >= n) return;
  float hid[32];
#pragma unroll
  for (int j = 0; j < 32; ++j) hid[j] = bc1[j];
  const float* hr = h + (size_t)row * 64;
#pragma unroll 4
  for (int k = 0; k < 64; k += 4) {
    float4 x = *(const float4*)&hr[k];
#pragma unroll
    for (int j = 0; j < 32; ++j) {
      hid[j] += x.x * Wc1[k * 32 + j] + x.y * Wc1[(k + 1) * 32 + j]
              + x.z * Wc1[(k + 2) * 32 + j] + x.w * Wc1[(k + 3) * 32 + j];
    }
  }
  float o0 = bc2[0], o1 = bc2[1];
#pragma unroll
  for (int j = 0; j < 32; ++j) {
    float v = fmaxf(hid[j], 0.f);
    o0 += v * Wc2[j * 2 + 0];
    o1 += v * Wc2[j * 2 + 1];
  }
  *(float2*)&out[(size_t)row * 2] = make_float2(o0, o1);
}

// ---------------------------------------------------------------------------
extern "C" void kernel_launch(void* const* d_in, const int* in_sizes, int n_in,
                              void* d_out, int out_size, void* d_ws, size_t ws_size,
                              hipStream_t stream)
{
  const float* x     = (const float*)d_in[0];
  const int*  eidx   = (const int*)d_in[1];
  const float* Wp    = (const float*)d_in[2];
  const float* bp    = (const float*)d_in[3];
  const float* Wk    = (const float*)d_in[4];
  const float* bk    = (const float*)d_in[5];
  const float* Wq    = (const float*)d_in[6];
  const float* bq    = (const float*)d_in[7];
  const float* Wv    = (const float*)d_in[8];
  const float* bv    = (const float*)d_in[9];
  const float* a_rel = (const float*)d_in[10];
  const float* m_rel = (const float*)d_in[11];
  const float* p_rel = (const float*)d_in[12];
  const float* Wo    = (const float*)d_in[13];
  const float* bo    = (const float*)d_in[14];
  const float* skip  = (const float*)d_in[15];
  const float* Wc1   = (const float*)d_in[16];
  const float* bc1   = (const float*)d_in[17];
  const float* Wc2   = (const float*)d_in[18];
  const float* bc2   = (const float*)d_in[19];
  float* out = (float*)d_out;

  const int N = in_sizes[0] / 768;
  const int E = in_sizes[1] / 2;
  const int* srcIdx = eidx;
  const int* dstIdx = eidx + E;

  char* ws = (char*)d_ws;
  size_t off = 0;
  auto alloc = [&](size_t bytes) -> void* {
    void* p = ws + off;
    off = (off + bytes + 255) & ~(size_t)255;
    return p;
  };
  float* h     = (float*)alloc((size_t)N * 64 * 4);
  float* qkv   = (float*)alloc((size_t)N * 192 * 4);
  float* agg   = (float*)alloc((size_t)N * 64 * 4);
  float* Wqkv  = (float*)alloc(2 * 64 * 192 * 4);
  float* bqkv  = (float*)alloc(2 * 192 * 4);
  int* row_ptr = (int*)alloc((size_t)(N + 1) * 4);
  int* cursor  = (int*)alloc((size_t)N * 4);
  int* counts  = (int*)alloc((size_t)N * 4);
  int* blockSums = (int*)alloc(512 * 4);
  int* csr_src = (int*)alloc((size_t)E * 4);
  // split-bf16 transposed weights [C][K]
  ushort* WtP_h   = (ushort*)alloc((size_t)64 * 768 * 2);
  ushort* WtP_l   = (ushort*)alloc((size_t)64 * 768 * 2);
  ushort* WtQKV_h = (ushort*)alloc((size_t)2 * 192 * 64 * 2);
  ushort* WtQKV_l = (ushort*)alloc((size_t)2 * 192 * 64 * 2);
  ushort* WtO_h   = (ushort*)alloc((size_t)2 * 64 * 64 * 2);
  ushort* WtO_l   = (ushort*)alloc((size_t)2 * 64 * 64 * 2);
  (void)ws_size; (void)n_in; (void)out_size;

  hipMemsetAsync(counts, 0, (size_t)N * 4, stream);

  fold_weights<<<2, 256, 0, stream>>>(Wq, bq, Wk, bk, Wv, bv, a_rel, m_rel, Wqkv, bqkv);

  // transpose + split all GEMM weights (tiny, once per launch)
  prep_weights<<<(768 * 64 + 255) / 256, 256, 0, stream>>>(Wp, 768, 64, WtP_h, WtP_l);
  for (int l = 0; l < 2; ++l) {
    prep_weights<<<(64 * 192 + 255) / 256, 256, 0, stream>>>(
        Wqkv + l * 64 * 192, 64, 192, WtQKV_h + l * 192 * 64, WtQKV_l + l * 192 * 64);
    prep_weights<<<(64 * 64 + 255) / 256, 256, 0, stream>>>(
        Wo + l * 4096, 64, 64, WtO_h + l * 4096, WtO_l + l * 4096);
  }

  // input projection: h = x @ Wp + bp
  mfma_gemm<768, false, false><<<dim3((N + 63) / 64, 1), 256, 0, stream>>>(
      x, 768, WtP_h, WtP_l, bp, nullptr, nullptr, h, 64, N);

  // CSR build (shared by both layers)
  hist_kernel<<<(E + 255) / 256, 256, 0, stream>>>(dstIdx, counts, E);
  int G = (N + 1023) / 1024;
  scanA<<<G, 256, 0, stream>>>(counts, blockSums, N);
  scanB<<<1, 128, 0, stream>>>(blockSums, G, row_ptr, N);
  scanC<<<(N + 255) / 256, 256, 0, stream>>>(counts, blockSums, row_ptr, cursor, N);
  scatter_kernel<<<(E + 255) / 256, 256, 0, stream>>>(srcIdx, dstIdx, cursor, csr_src, E);

  for (int l = 0; l < 2; ++l) {
    // fused q | kt | vt projection: [N,64] @ [64,192]
    mfma_gemm<64, false, false><<<dim3((N + 63) / 64, 3), 256, 0, stream>>>(
        h, 64, WtQKV_h + l * 192 * 64, WtQKV_l + l * 192 * 64, bqkv + l * 192,
        nullptr, nullptr, qkv, 192, N);
    // attention + aggregation
    edge_agg<<<(N + 3) / 4, 256, 0, stream>>>(qkv, row_ptr, csr_src, p_rel + l * 4, agg, N);
    // out = relu(g*(gelu(agg)@Wo + bo) + (1-g)*h), in-place into h
    mfma_gemm<64, true, true><<<dim3((N + 63) / 64, 1), 256, 0, stream>>>(
        agg, 64, WtO_h + l * 4096, WtO_l + l * 4096, bo + l * 64, h, skip + l, h, 64, N);
  }

  classifier<<<(N + 255) / 256, 256, 0, stream>>>(h, Wc1, bc1, Wc2, bc2, out, N);
}

// Round 5
// 1194.456 us; speedup vs baseline: 1.1448x; 1.1448x over previous
//
#include <hip/hip_runtime.h>
#include <math.h>

// ---------------------------------------------------------------------------
// SimpleLESS4FDModel: 2-layer HGT on a homogeneous graph.
// a_rel / m_rel folded into projection weights (fold_weights).
// Per edge:  alpha = <kt[src], q[dst]>_head * p_rel / 4 ;
//   agg[dst] = sum_e exp(alpha) * vt[src] / (sum_e exp(alpha) + 1e-16)
// CSR (built once, reused by both layers) makes aggregation atomic-free.
//
// R1: no runtime-indexed local arrays (scratch). R2: bound unrolls, cap VGPRs.
// R3: fp32 vector GEMM LDS-pipe-bound -> split-bf16 MFMA (ah*bh+ah*bl+al*bh).
// R4 lesson: direct-from-global fragments with VGPR_Count=28 serialize on
// vmcnt(0) every chunk (234us, 9.6% HBM). Fix: m97-style LDS-staged K-loop —
// chunk-contiguous B layout (coalesced, staged once per block), A pre-split
// into LDS, depth-1 register prefetch of the next chunk's global loads.
// ---------------------------------------------------------------------------

typedef __attribute__((ext_vector_type(8))) short bf16x8;  // 8 bf16 (4 VGPRs)
typedef __attribute__((ext_vector_type(4))) float f32x4;

__device__ __forceinline__ float gelu_t(float x) {
  const float c = 0.7978845608028654f;  // sqrt(2/pi)
  float t = tanhf(c * (x + 0.044715f * x * x * x));
  return 0.5f * x * (1.0f + t);
}

// split fp32 -> bf16 hi (truncate) + bf16 lo (truncate of remainder)
__device__ __forceinline__ void split1(float a, ushort& h, ushort& l) {
  unsigned u = __float_as_uint(a);
  unsigned uh = u & 0xffff0000u;
  float fl = a - __uint_as_float(uh);
  h = (ushort)(uh >> 16);
  l = (ushort)(__float_as_uint(fl) >> 16);
}

// ---------------- split-bf16 MFMA GEMM, LDS-staged ---------------------------
// out[r, colBlk+c] = epi(A[r,:] @ W[:,c] + bias[c])
// Block: 256 threads = 4 waves; 64 rows x 64 cols per block.
// Wt layout (ushort): per colBlk cb, per 32-k chunk ch: 4096 ushorts =
//   [h: c(64) x k(32)] ++ [l: c(64) x k(32)]   (contiguous 8 KB per chunk)
template<int K, bool PRE_GELU, bool EPI_SKIP>
__global__ __launch_bounds__(256, 4)
void mfma_gemm(const float* __restrict__ A, int ldA,
               const ushort* __restrict__ Wt,
               const float* __restrict__ bias,
               const float* __restrict__ Hprev,
               const float* __restrict__ skipPtr,
               float* __restrict__ outp, int ldOut, int nRows)
{
  constexpr int NCH = K / 32;
  __shared__ ushort sA[2 * 64 * 32];  // h at 0, l at +2048 (8 KB)
  __shared__ ushort sB[2 * 64 * 32];  // h at 0, l at +2048 (8 KB)
  const int tid = threadIdx.x;
  const int lane = tid & 63;
  const int wv = tid >> 6;
  const int m = lane & 15;   // A row / B col / C col within tile
  const int q = lane >> 4;   // quad
  const int row0 = blockIdx.x * 64;
  const int colBlk = blockIdx.y * 64;

  // staging roles: thread t stages A row (t>>2), k-offset (t&3)*8 (32 B)
  const int srow = tid >> 2;
  const int skoff = (tid & 3) * 8;
  int gr = row0 + srow; if (gr >= nRows) gr = nRows - 1;  // clamp; masked at store
  const float* aBase = A + (size_t)gr * ldA + skoff;
  const float4* wBase = (const float4*)(Wt + (size_t)blockIdx.y * NCH * 4096);

  f32x4 acc[4];
#pragma unroll
  for (int ct = 0; ct < 4; ++ct) acc[ct] = (f32x4){0.f, 0.f, 0.f, 0.f};

  // prefetch chunk 0 into registers
  float4 a0 = *(const float4*)(aBase + 0);
  float4 a1 = *(const float4*)(aBase + 4);
  float4 b0 = wBase[tid * 2];
  float4 b1 = wBase[tid * 2 + 1];

#pragma clang loop unroll(disable)
  for (int ch = 0; ch < NCH; ++ch) {
    float4 na0 = a0, na1 = a1, nb0 = b0, nb1 = b1;
    if (ch + 1 < NCH) {  // issue next chunk's global loads before consuming cur
      na0 = *(const float4*)(aBase + (ch + 1) * 32);
      na1 = *(const float4*)(aBase + (ch + 1) * 32 + 4);
      const float4* wc = wBase + (size_t)(ch + 1) * 512;  // 4096 ushorts = 512 float4
      nb0 = wc[tid * 2];
      nb1 = wc[tid * 2 + 1];
    }
    // split current A (gelu once, at stage time)
    float av[8] = {a0.x, a0.y, a0.z, a0.w, a1.x, a1.y, a1.z, a1.w};
    if (PRE_GELU) {
#pragma unroll
      for (int j = 0; j < 8; ++j) av[j] = gelu_t(av[j]);
    }
    bf16x8 vh, vl;
#pragma unroll
    for (int j = 0; j < 8; ++j) {
      ushort h, l; split1(av[j], h, l);
      vh[j] = (short)h; vl[j] = (short)l;
    }
    __syncthreads();  // previous chunk's LDS reads complete before overwrite
    *(bf16x8*)(sA + srow * 32 + skoff) = vh;
    *(bf16x8*)(sA + 2048 + srow * 32 + skoff) = vl;
    ((float4*)sB)[tid * 2] = b0;
    ((float4*)sB)[tid * 2 + 1] = b1;
    __syncthreads();
    // fragments from LDS (all conflict-free b128 patterns) + 12 MFMAs
    bf16x8 ah = *(const bf16x8*)(sA + (wv * 16 + m) * 32 + q * 8);
    bf16x8 al = *(const bf16x8*)(sA + 2048 + (wv * 16 + m) * 32 + q * 8);
#pragma unroll
    for (int ct = 0; ct < 4; ++ct) {
      bf16x8 bh = *(const bf16x8*)(sB + (ct * 16 + m) * 32 + q * 8);
      bf16x8 bl = *(const bf16x8*)(sB + 2048 + (ct * 16 + m) * 32 + q * 8);
      acc[ct] = __builtin_amdgcn_mfma_f32_16x16x32_bf16(ah, bh, acc[ct], 0, 0, 0);
      acc[ct] = __builtin_amdgcn_mfma_f32_16x16x32_bf16(ah, bl, acc[ct], 0, 0, 0);
      acc[ct] = __builtin_amdgcn_mfma_f32_16x16x32_bf16(al, bh, acc[ct], 0, 0, 0);
    }
    a0 = na0; a1 = na1; b0 = nb0; b1 = nb1;
  }

  // epilogue: C/D layout col = lane&15 (=m), row = quad*4 + reg  [m89-verified]
  float g = 0.f, gi = 0.f;
  if (EPI_SKIP) { g = 1.0f / (1.0f + __expf(-skipPtr[0])); gi = 1.0f - g; }
#pragma unroll
  for (int ct = 0; ct < 4; ++ct) {
    int c = colBlk + ct * 16 + m;
    float b = bias[c];
#pragma unroll
    for (int i = 0; i < 4; ++i) {
      int r = row0 + wv * 16 + q * 4 + i;
      if (r < nRows) {
        float o = acc[ct][i] + b;
        if (EPI_SKIP) {
          float hp = Hprev[(size_t)r * 64 + c];
          o = fmaxf(g * o + gi * hp, 0.f);
        }
        outp[(size_t)r * ldOut + c] = o;
      }
    }
  }
}

// ---------------- weight transpose + bf16 split into chunked layout ----------
// W[k][c] (row-major, ld=C) -> Wt chunk layout (see mfma_gemm header comment)
__global__ void prep_weights(const float* __restrict__ W, int K, int C,
                             ushort* __restrict__ Wt)
{
  int idx = blockIdx.x * 256 + threadIdx.x;
  if (idx < K * C) {
    int k = idx / C, c = idx % C;
    ushort h, l; split1(W[idx], h, l);
    int cb = c >> 6, cc = c & 63, ch = k >> 5, kk = k & 31;
    size_t base = (size_t)(cb * (K >> 5) + ch) * 4096;
    Wt[base + cc * 32 + kk] = h;
    Wt[base + 2048 + cc * 32 + kk] = l;
  }
}

// ---------------- fold a_rel / m_rel into packed qkv weights ------------------
// Wqkv[l]: [64][192]  cols 0..63 = Wq, 64..127 = Wk@BD(a_rel), 128..191 = Wv@BD(m_rel)
__global__ void fold_weights(const float* __restrict__ Wq, const float* __restrict__ bq,
                             const float* __restrict__ Wk, const float* __restrict__ bk,
                             const float* __restrict__ Wv, const float* __restrict__ bv,
                             const float* __restrict__ a_rel, const float* __restrict__ m_rel,
                             float* __restrict__ Wqkv, float* __restrict__ bqkv)
{
  int l = blockIdx.x;
  const float* wq = Wq + l * 4096; const float* wk = Wk + l * 4096; const float* wv = Wv + l * 4096;
  const float* bql = bq + l * 64;  const float* bkl = bk + l * 64;  const float* bvl = bv + l * 64;
  const float* ar = a_rel + l * 1024; const float* mr = m_rel + l * 1024;
  float* W = Wqkv + l * 64 * 192;  float* B = bqkv + l * 192;
  for (int t = threadIdx.x; t < 64 * 192; t += blockDim.x) {
    int i = t / 192, c = t % 192;
    float val;
    if (c < 64) {
      val = wq[i * 64 + c];
    } else if (c < 128) {
      int cc = c - 64, hh = cc >> 4, f = cc & 15;
      float s = 0.f;
      for (int d = 0; d < 16; ++d) s += wk[i * 64 + hh * 16 + d] * ar[hh * 256 + d * 16 + f];
      val = s;
    } else {
      int cc = c - 128, hh = cc >> 4, f = cc & 15;
      float s = 0.f;
      for (int d = 0; d < 16; ++d) s += wv[i * 64 + hh * 16 + d] * mr[hh * 256 + d * 16 + f];
      val = s;
    }
    W[i * 192 + c] = val;
  }
  for (int c = threadIdx.x; c < 192; c += blockDim.x) {
    float val;
    if (c < 64) {
      val = bql[c];
    } else if (c < 128) {
      int cc = c - 64, hh = cc >> 4, f = cc & 15;
      float s = 0.f;
      for (int d = 0; d < 16; ++d) s += bkl[hh * 16 + d] * ar[hh * 256 + d * 16 + f];
      val = s;
    } else {
      int cc = c - 128, hh = cc >> 4, f = cc & 15;
      float s = 0.f;
      for (int d = 0; d < 16; ++d) s += bvl[hh * 16 + d] * mr[hh * 256 + d * 16 + f];
      val = s;
    }
    B[c] = val;
  }
}

// ---------------- CSR construction -------------------------------------------
__global__ void hist_kernel(const int* __restrict__ dst, int* __restrict__ counts, int E) {
  int e = blockIdx.x * 256 + threadIdx.x;
  if (e < E) atomicAdd(&counts[dst[e]], 1);
}

__global__ __launch_bounds__(256)
void scanA(int* __restrict__ counts, int* __restrict__ blockSums, int n) {
  __shared__ int sd[256];
  int tid = threadIdx.x;
  int base = blockIdx.x * 1024 + tid * 4;
  int v[4];
#pragma unroll
  for (int j = 0; j < 4; ++j) v[j] = (base + j < n) ? counts[base + j] : 0;
  int t = v[0] + v[1] + v[2] + v[3];
  sd[tid] = t; __syncthreads();
  for (int offm = 1; offm < 256; offm <<= 1) {
    int adj = (tid >= offm) ? sd[tid - offm] : 0;
    __syncthreads();
    sd[tid] += adj;
    __syncthreads();
  }
  int run = sd[tid] - t;  // exclusive prefix for this thread
#pragma unroll
  for (int j = 0; j < 4; ++j) {
    if (base + j < n) counts[base + j] = run;
    run += v[j];
  }
  if (tid == 255) blockSums[blockIdx.x] = sd[255];
}

__global__ void scanB(int* __restrict__ blockSums, int G, int* __restrict__ row_ptr, int n) {
  __shared__ int sd[128];
  int tid = threadIdx.x;
  int t = (tid < G) ? blockSums[tid] : 0;
  sd[tid] = t; __syncthreads();
  for (int offm = 1; offm < 128; offm <<= 1) {
    int adj = (tid >= offm) ? sd[tid - offm] : 0;
    __syncthreads();
    sd[tid] += adj;
    __syncthreads();
  }
  if (tid < G) blockSums[tid] = sd[tid] - t;
  if (tid == 127) row_ptr[n] = sd[127];  // total = E
}

__global__ void scanC(const int* __restrict__ counts, const int* __restrict__ blockSums,
                      int* __restrict__ row_ptr, int* __restrict__ cursor, int n) {
  int idx = blockIdx.x * 256 + threadIdx.x;
  if (idx < n) {
    int v = counts[idx] + blockSums[idx >> 10];
    row_ptr[idx] = v;
    cursor[idx] = v;
  }
}

__global__ void scatter_kernel(const int* __restrict__ src, const int* __restrict__ dst,
                               int* __restrict__ cursor, int* __restrict__ csr_src, int E) {
  int e = blockIdx.x * 256 + threadIdx.x;
  if (e < E) {
    int d = dst[e];
    int pos = atomicAdd(&cursor[d], 1);
    csr_src[pos] = src[e];
  }
}

// ---------------- fused attention aggregation: one wave per dst node ----------
// lane = head*16 + f. qkv row layout: [q(64) | kt(64) | vt(64)], ld=192.
__global__ __launch_bounds__(256)
void edge_agg(const float* __restrict__ qkv, const int* __restrict__ row_ptr,
              const int* __restrict__ csr_src, const float* __restrict__ p_rel,
              float* __restrict__ agg, int n)
{
  int wid = blockIdx.x * 4 + (threadIdx.x >> 6);
  if (wid >= n) return;
  int lane = threadIdx.x & 63;
  int head = lane >> 4;
  float pr = p_rel[head] * 0.25f;  // p_rel / sqrt(D), D=16
  float qv = qkv[(size_t)wid * 192 + lane];
  int e0 = row_ptr[wid], e1 = row_ptr[wid + 1];
  float num = 0.f, den = 0.f;
  for (int e = e0; e < e1; ++e) {
    int s = csr_src[e];
    const float* base = qkv + (size_t)s * 192;
    float ktv = base[64 + lane];
    float vtv = base[128 + lane];
    float p = ktv * qv;
    p += __shfl_xor(p, 1);
    p += __shfl_xor(p, 2);
    p += __shfl_xor(p, 4);
    p += __shfl_xor(p, 8);   // per-head dot over 16 lanes
    float w = __expf(p * pr);
    den += w;
    num = fmaf(w, vtv, num);
  }
  agg[(size_t)wid * 64 + lane] = num / (den + 1e-16f);
}

// ---------------- classifier: 64 -> relu(32) -> 2 ----------------------------
__global__ __launch_bounds__(256)
void classifier(const float* __restrict__ h, const float* __restrict__ Wc1,
                const float* __restrict__ bc1, const float* __restrict__ Wc2,
                const float* __restrict__ bc2, float* __restrict__ out, int n)
{
  int row = blockIdx.x * 256 + threadIdx.x;
  if (row >= n) return;
  float hid[32];
#pragma unroll
  for (int j = 0; j < 32; ++j) hid[j] = bc1[j];
  const float* hr = h + (size_t)row * 64;
#pragma unroll 4
  for (int k = 0; k < 64; k += 4) {
    float4 x = *(const float4*)&hr[k];
#pragma unroll
    for (int j = 0; j < 32; ++j) {
      hid[j] += x.x * Wc1[k * 32 + j] + x.y * Wc1[(k + 1) * 32 + j]
              + x.z * Wc1[(k + 2) * 32 + j] + x.w * Wc1[(k + 3) * 32 + j];
    }
  }
  float o0 = bc2[0], o1 = bc2[1];
#pragma unroll
  for (int j = 0; j < 32; ++j) {
    float v = fmaxf(hid[j], 0.f);
    o0 += v * Wc2[j * 2 + 0];
    o1 += v * Wc2[j * 2 + 1];
  }
  *(float2*)&out[(size_t)row * 2] = make_float2(o0, o1);
}

// ---------------------------------------------------------------------------
extern "C" void kernel_launch(void* const* d_in, const int* in_sizes, int n_in,
                              void* d_out, int out_size, void* d_ws, size_t ws_size,
                              hipStream_t stream)
{
  const float* x     = (const float*)d_in[0];
  const int*  eidx   = (const int*)d_in[1];
  const float* Wp    = (const float*)d_in[2];
  const float* bp    = (const float*)d_in[3];
  const float* Wk    = (const float*)d_in[4];
  const float* bk    = (const float*)d_in[5];
  const float* Wq    = (const float*)d_in[6];
  const float* bq    = (const float*)d_in[7];
  const float* Wv    = (const float*)d_in[8];
  const float* bv    = (const float*)d_in[9];
  const float* a_rel = (const float*)d_in[10];
  const float* m_rel = (const float*)d_in[11];
  const float* p_rel = (const float*)d_in[12];
  const float* Wo    = (const float*)d_in[13];
  const float* bo    = (const float*)d_in[14];
  const float* skip  = (const float*)d_in[15];
  const float* Wc1   = (const float*)d_in[16];
  const float* bc1   = (const float*)d_in[17];
  const float* Wc2   = (const float*)d_in[18];
  const float* bc2   = (const float*)d_in[19];
  float* out = (float*)d_out;

  const int N = in_sizes[0] / 768;
  const int E = in_sizes[1] / 2;
  const int* srcIdx = eidx;
  const int* dstIdx = eidx + E;

  char* ws = (char*)d_ws;
  size_t off = 0;
  auto alloc = [&](size_t bytes) -> void* {
    void* p = ws + off;
    off = (off + bytes + 255) & ~(size_t)255;
    return p;
  };
  float* h     = (float*)alloc((size_t)N * 64 * 4);
  float* qkv   = (float*)alloc((size_t)N * 192 * 4);
  float* agg   = (float*)alloc((size_t)N * 64 * 4);
  float* Wqkv  = (float*)alloc(2 * 64 * 192 * 4);
  float* bqkv  = (float*)alloc(2 * 192 * 4);
  int* row_ptr = (int*)alloc((size_t)(N + 1) * 4);
  int* cursor  = (int*)alloc((size_t)N * 4);
  int* counts  = (int*)alloc((size_t)N * 4);
  int* blockSums = (int*)alloc(512 * 4);
  int* csr_src = (int*)alloc((size_t)E * 4);
  // split-bf16 chunked weights (h+l interleaved per 64x32 chunk)
  ushort* WtP   = (ushort*)alloc((size_t)64 * 768 * 2 * 2);
  ushort* WtQKV = (ushort*)alloc((size_t)2 * 192 * 64 * 2 * 2);
  ushort* WtO   = (ushort*)alloc((size_t)2 * 64 * 64 * 2 * 2);
  (void)ws_size; (void)n_in; (void)out_size;

  hipMemsetAsync(counts, 0, (size_t)N * 4, stream);

  fold_weights<<<2, 256, 0, stream>>>(Wq, bq, Wk, bk, Wv, bv, a_rel, m_rel, Wqkv, bqkv);

  // transpose + split all GEMM weights into chunked layout (tiny, once)
  prep_weights<<<(768 * 64 + 255) / 256, 256, 0, stream>>>(Wp, 768, 64, WtP);
  for (int l = 0; l < 2; ++l) {
    prep_weights<<<(64 * 192 + 255) / 256, 256, 0, stream>>>(
        Wqkv + l * 64 * 192, 64, 192, WtQKV + (size_t)l * 192 * 64 * 2);
    prep_weights<<<(64 * 64 + 255) / 256, 256, 0, stream>>>(
        Wo + l * 4096, 64, 64, WtO + (size_t)l * 64 * 64 * 2);
  }

  // input projection: h = x @ Wp + bp
  mfma_gemm<768, false, false><<<dim3((N + 63) / 64, 1), 256, 0, stream>>>(
      x, 768, WtP, bp, nullptr, nullptr, h, 64, N);

  // CSR build (shared by both layers)
  hist_kernel<<<(E + 255) / 256, 256, 0, stream>>>(dstIdx, counts, E);
  int G = (N + 1023) / 1024;
  scanA<<<G, 256, 0, stream>>>(counts, blockSums, N);
  scanB<<<1, 128, 0, stream>>>(blockSums, G, row_ptr, N);
  scanC<<<(N + 255) / 256, 256, 0, stream>>>(counts, blockSums, row_ptr, cursor, N);
  scatter_kernel<<<(E + 255) / 256, 256, 0, stream>>>(srcIdx, dstIdx, cursor, csr_src, E);

  for (int l = 0; l < 2; ++l) {
    // fused q | kt | vt projection: [N,64] @ [64,192]
    mfma_gemm<64, false, false><<<dim3((N + 63) / 64, 3), 256, 0, stream>>>(
        h, 64, WtQKV + (size_t)l * 192 * 64 * 2, bqkv + l * 192,
        nullptr, nullptr, qkv, 192, N);
    // attention + aggregation
    edge_agg<<<(N + 3) / 4, 256, 0, stream>>>(qkv, row_ptr, csr_src, p_rel + l * 4, agg, N);
    // out = relu(g*(gelu(agg)@Wo + bo) + (1-g)*h), in-place into h
    mfma_gemm<64, true, true><<<dim3((N + 63) / 64, 1), 256, 0, stream>>>(
        agg, 64, WtO + (size_t)l * 64 * 64 * 2, bo + l * 64, h, skip + l, h, 64, N);
  }

  classifier<<<(N + 255) / 256, 256, 0, stream>>>(h, Wc1, bc1, Wc2, bc2, out, N);
}